// Round 3
// baseline (930.310 us; speedup 1.0000x reference)
//
#include <hip/hip_runtime.h>
#include <stdint.h>

#define NN 65536

typedef __attribute__((ext_vector_type(8))) short bf16x8;
typedef __attribute__((ext_vector_type(4))) float f32x4;

__device__ __forceinline__ unsigned short f2bf(float f) {
    unsigned u = __float_as_uint(f);
    u += 0x7fffu + ((u >> 16) & 1u);
    return (unsigned short)(u >> 16);
}
__device__ __forceinline__ float bf2f(unsigned short h) { return __uint_as_float(((unsigned)h) << 16); }
__device__ __forceinline__ float blo(unsigned u) { return __uint_as_float(u << 16); }
__device__ __forceinline__ float bhi(unsigned u) { return __uint_as_float(u & 0xffff0000u); }
__device__ __forceinline__ unsigned pack2(float a, float b) {
    return ((unsigned)f2bf(b) << 16) | (unsigned)f2bf(a);
}
// lo16 = hi16(x) [trunc-to-bf16], hi16 = hi16(y)
__device__ __forceinline__ unsigned trunc2(float x, float y) {
    return __builtin_amdgcn_perm(__float_as_uint(y), __float_as_uint(x), 0x07060302u);
}

__device__ __forceinline__ void gl_lds16(const void* g, void* l) {
    __builtin_amdgcn_global_load_lds((const __attribute__((address_space(1))) void*)g,
                                     (__attribute__((address_space(3))) void*)l, 16, 0, 0);
}

// ---------------- prep: pack/transpose weights to bf16 ----------------
__global__ void prep_pack(const float* Wt1, const float* Wt2, const float* W1,
                          const float* W2, const float* Mtx,
                          unsigned short* Wcat, unsigned short* W1T,
                          unsigned short* W2T, unsigned short* MTh, unsigned short* MTl) {
    int i = blockIdx.x * 256 + threadIdx.x;
    if (i < 524288) {                       // Wcat [1024][512]
        int k = i >> 9, j = i & 511;
        float v = (k < 256) ? Wt1[k * 512 + j] : Wt2[(k - 256) * 512 + j];
        Wcat[i] = f2bf(v);
    } else if (i < 786432) {                // W1T [512][512]
        int t = i - 524288; int n = t >> 9, j = t & 511;
        W1T[t] = f2bf(W1[j * 512 + n]);
    } else if (i < 851968) {                // W2T [128][512]
        int t = i - 786432; int n = t >> 9, j = t & 511;
        W2T[t] = f2bf(W2[j * 128 + n]);
    } else if (i < 868352) {                // MT [128][128] hi/lo, MT[r][c]=M[c][r]
        int t = i - 851968; int d = t >> 7, e = t & 127;
        float m = Mtx[e * 128 + d];
        unsigned short h = f2bf(m);
        MTh[t] = h; MTl[t] = f2bf(m - bf2f(h));
    }
}

// cbias = (bt1+bt2) @ W1 — 16 blocks, K-partitioned reduction
__global__ void cbias_k(const float* bt1, const float* bt2, const float* W1, float* c) {
    __shared__ float sm[256];
    int t = threadIdx.x;
    int n = blockIdx.x * 32 + (t & 31);
    int jp = t >> 5;                        // 8 K-partitions of 64
    float acc = 0.f;
    for (int j = jp * 64; j < jp * 64 + 64; j++)
        acc += (bt1[j] + bt2[j]) * W1[j * 512 + n];
    sm[t] = acc;
    __syncthreads();
    if (t < 32) {
        float a = 0.f;
#pragma unroll
        for (int p = 0; p < 8; p++) a += sm[p * 32 + t];
        c[blockIdx.x * 32 + t] = a;
    }
}

// ---------------- CSR build ----------------
__global__ void count_k(const int* dst, int* cnt, int E) {
    int e = blockIdx.x * 256 + threadIdx.x;
    if (e < E) atomicAdd(&cnt[dst[e]], 1);
}
__global__ void red_k(const int* cnt, int* bsum) {
    __shared__ int sm[256];
    int tid = threadIdx.x;
    sm[tid] = cnt[blockIdx.x * 256 + tid];
    __syncthreads();
    for (int s = 128; s > 0; s >>= 1) {
        if (tid < s) sm[tid] += sm[tid + s];
        __syncthreads();
    }
    if (tid == 0) bsum[blockIdx.x] = sm[0];
}
__global__ void scanb_k(const int* bsum, int* boff) {
    __shared__ int sm[256];
    int tid = threadIdx.x;
    int v0 = bsum[tid];
    sm[tid] = v0;
    __syncthreads();
    for (int s = 1; s < 256; s <<= 1) {
        int t = sm[tid];
        if (tid >= s) t += sm[tid - s];
        __syncthreads();
        sm[tid] = t;
        __syncthreads();
    }
    boff[tid] = sm[tid] - v0;   // exclusive
}
__global__ void scanf_k(const int* cnt, const int* boff, int* rowptr, int* cursor, float* invs) {
    __shared__ int sm[256];
    int tid = threadIdx.x;
    int i = blockIdx.x * 256 + tid;
    int v = cnt[i];
    sm[tid] = v;
    __syncthreads();
    for (int s = 1; s < 256; s <<= 1) {
        int t = sm[tid];
        if (tid >= s) t += sm[tid - s];
        __syncthreads();
        sm[tid] = t;
        __syncthreads();
    }
    int incl = sm[tid];
    int base = boff[blockIdx.x];
    int excl = base + incl - v;
    rowptr[i] = excl;
    cursor[i] = excl;
    invs[i] = rsqrtf((float)(v + 1));
    if (i == NN - 1) rowptr[NN] = base + incl;
}
__global__ void fill_k(const int* src, const int* dst, int* cursor, int* colv, int E) {
    int e = blockIdx.x * 256 + threadIdx.x;
    if (e < E) {
        int d = dst[e];
        int p = atomicAdd(&cursor[d], 1);
        colv[p] = src[e];
    }
}

// ---------------- generic bf16 GEMM: C[M,N] = A[M,K] @ BT[N,K]^T (+bias[col]) * rs[row] ----------------
__global__ __launch_bounds__(256, 2) void gemm_bt(const unsigned short* A, const unsigned short* BT,
                                                  unsigned short* C, const float* bias,
                                                  const float* rs,
                                                  int M, int N, int K) {
    __shared__ __align__(16) unsigned short sA[128 * 32];
    __shared__ __align__(16) unsigned short sB[128 * 32];
    int tid = threadIdx.x, wave = tid >> 6, lane = tid & 63;
    int bm = blockIdx.y * 128, bn = blockIdx.x * 128;
    int wm = (wave >> 1) * 64, wn = (wave & 1) * 64;
    f32x4 acc[4][4];
#pragma unroll
    for (int i = 0; i < 4; i++)
#pragma unroll
        for (int j = 0; j < 4; j++) acc[i][j] = (f32x4){0.f, 0.f, 0.f, 0.f};
    int sr = wave * 32 + (lane >> 2);
    int sc = (lane & 3) * 8;
    const int fr = lane & 15;
    const int fk = (lane >> 4) * 8;
    for (int k0 = 0; k0 < K; k0 += 32) {
        const unsigned short* ga = A + (size_t)(bm + sr) * K + k0 + sc;
        gl_lds16(ga, &sA[sr * 32 + sc]);
        gl_lds16(ga + (size_t)16 * K, &sA[(sr + 16) * 32 + sc]);
        const unsigned short* gb = BT + (size_t)(bn + sr) * K + k0 + sc;
        gl_lds16(gb, &sB[sr * 32 + sc]);
        gl_lds16(gb + (size_t)16 * K, &sB[(sr + 16) * 32 + sc]);
        __syncthreads();
        bf16x8 af[4], bfr[4];
#pragma unroll
        for (int i = 0; i < 4; i++) af[i] = *(const bf16x8*)&sA[(wm + i * 16 + fr) * 32 + fk];
#pragma unroll
        for (int j = 0; j < 4; j++) bfr[j] = *(const bf16x8*)&sB[(wn + j * 16 + fr) * 32 + fk];
#pragma unroll
        for (int i = 0; i < 4; i++)
#pragma unroll
            for (int j = 0; j < 4; j++)
                acc[i][j] = __builtin_amdgcn_mfma_f32_16x16x32_bf16(af[i], bfr[j], acc[i][j], 0, 0, 0);
        __syncthreads();
    }
    int rq = (lane >> 4) * 4;
#pragma unroll
    for (int i = 0; i < 4; i++)
#pragma unroll
        for (int j = 0; j < 4; j++) {
            int col = bn + wn + j * 16 + fr;
            float bb = bias ? bias[col] : 0.f;
#pragma unroll
            for (int r = 0; r < 4; r++) {
                int row = bm + wm + i * 16 + rq + r;
                float scale = rs ? rs[row] : 1.f;
                C[(size_t)row * N + col] = f2bf((acc[i][j][r] + bb) * scale);
            }
        }
}

// ---------------- GEMM1: t1 = x[65536,1024] @ WcombT^T + cbias, row-scaled by invs ----------------
// v2: reg-staged bf16 A. Per thread: 4x global float4 (row tid>>1, half tid&1),
// trunc2-pack to bf16 in regs, 2x ds_write_b128 into padded sA[128][40] (80B row
// stride -> fragment reads are ~2-way bank conflicts instead of 8-way; halves
// A ds_read count vs fp32-in-LDS). Double-buffered 1-barrier K-loop: next-tile
// A loads + B DMA issued before MFMA (latency hides under MFMA), pack+write
// after MFMA into buf^1; the compiler's vmcnt/lgkmcnt drain at __syncthreads
// makes the buffer handoff safe. B stays gl_lds-staged (proven layout).
__global__ __launch_bounds__(256, 2) void gemm_f32a(const float* A, const unsigned short* BT,
                                                    unsigned short* C, const float* bias,
                                                    const float* rs) {
    const int K = 1024, N = 512;
    __shared__ __align__(16) unsigned short sA[2][128 * 40];   // 2 x 10 KB, padded stride 40
    __shared__ __align__(16) unsigned short sB[2][128 * 32];   // 2 x 8 KB
    int tid = threadIdx.x, wave = tid >> 6, lane = tid & 63;
    int b = blockIdx.x;
    int xcd = b & 7, jn = (b >> 3) & 3, tt = b >> 5;
    int bm = (tt * 8 + xcd) * 128, bn = jn * 128;
    int wm = (wave >> 1) * 64, wn = (wave & 1) * 64;
    f32x4 acc[4][4];
#pragma unroll
    for (int i = 0; i < 4; i++)
#pragma unroll
        for (int j = 0; j < 4; j++) acc[i][j] = (f32x4){0.f, 0.f, 0.f, 0.f};
    // B staging (bf16, proven layout)
    int sr = wave * 32 + (lane >> 2);
    int sc = (lane & 3) * 8;
    const unsigned short* Bbase = BT + (size_t)(bn + sr) * K + sc;
    // A staging: thread t -> row t>>1, half t&1 (16 floats = 64B per thread)
    int arow = tid >> 1, ahalf = tid & 1;
    const float* Abase = A + (size_t)(bm + arow) * K + ahalf * 16;
    unsigned short* wptr = &sA[0][0] + arow * 40 + ahalf * 16;  // buffer 1 at +128*40
    const int fr = lane & 15;
    const int fk = (lane >> 4) * 8;

    float4 la0, la1, la2, la3;
#define LDA(k0)                                        \
    do {                                               \
        const float* ap = Abase + (k0);                \
        la0 = *(const float4*)(ap);                    \
        la1 = *(const float4*)(ap + 4);                \
        la2 = *(const float4*)(ap + 8);                \
        la3 = *(const float4*)(ap + 12);               \
    } while (0)
#define GLB(k0, c)                                                         \
    do {                                                                   \
        gl_lds16(Bbase + (k0), &sB[c][sr * 32 + sc]);                      \
        gl_lds16(Bbase + (size_t)16 * K + (k0), &sB[c][(sr + 16) * 32 + sc]); \
    } while (0)
#define PACKW(c)                                                 \
    do {                                                         \
        union { unsigned u[8]; uint4 q[2]; } t;                  \
        t.u[0] = trunc2(la0.x, la0.y);                           \
        t.u[1] = trunc2(la0.z, la0.w);                           \
        t.u[2] = trunc2(la1.x, la1.y);                           \
        t.u[3] = trunc2(la1.z, la1.w);                           \
        t.u[4] = trunc2(la2.x, la2.y);                           \
        t.u[5] = trunc2(la2.z, la2.w);                           \
        t.u[6] = trunc2(la3.x, la3.y);                           \
        t.u[7] = trunc2(la3.z, la3.w);                           \
        unsigned short* dst = wptr + (c) * (128 * 40);           \
        *(uint4*)dst = t.q[0];                                   \
        *(uint4*)(dst + 8) = t.q[1];                             \
    } while (0)

    // prologue: stage tile 0 into buffer 0
    LDA(0);
    GLB(0, 0);
    PACKW(0);
    __syncthreads();
    for (int k0 = 0; k0 < K; k0 += 32) {
        int c = (k0 >> 5) & 1;
        bool more = (k0 + 32 < K);
        if (more) {
            LDA(k0 + 32);          // lands during MFMA phase
            GLB(k0 + 32, c ^ 1);   // DMA into the other buffer
        }
        bf16x8 af[4], bfr[4];
#pragma unroll
        for (int i = 0; i < 4; i++) af[i] = *(const bf16x8*)&sA[c][(wm + i * 16 + fr) * 40 + fk];
#pragma unroll
        for (int j = 0; j < 4; j++) bfr[j] = *(const bf16x8*)&sB[c][(wn + j * 16 + fr) * 32 + fk];
#pragma unroll
        for (int i = 0; i < 4; i++)
#pragma unroll
            for (int j = 0; j < 4; j++)
                acc[i][j] = __builtin_amdgcn_mfma_f32_16x16x32_bf16(af[i], bfr[j], acc[i][j], 0, 0, 0);
        if (more) PACKW(c ^ 1);
        __syncthreads();
    }
#undef LDA
#undef GLB
#undef PACKW
    int rq = (lane >> 4) * 4;
#pragma unroll
    for (int i = 0; i < 4; i++)
#pragma unroll
        for (int j = 0; j < 4; j++) {
            int col = bn + wn + j * 16 + fr;
            float bb = bias[col];
#pragma unroll
            for (int r = 0; r < 4; r++) {
                int row = bm + wm + i * 16 + rq + r;
                C[(size_t)row * N + col] = f2bf((acc[i][j][r] + bb) * rs[row]);
            }
        }
}

// ---------------- T = h2 @ M with hi/lo split (3 phases), split output ----------------
__global__ __launch_bounds__(256, 2) void gemm_T(const unsigned short* h2h, const unsigned short* h2l,
                                                 const unsigned short* MTh, const unsigned short* MTl,
                                                 unsigned short* Th, unsigned short* Tl) {
    __shared__ __align__(16) unsigned short sA[128 * 32];
    __shared__ __align__(16) unsigned short sB[128 * 32];
    int tid = threadIdx.x, wave = tid >> 6, lane = tid & 63;
    int bm = blockIdx.x * 128;
    int wm = (wave >> 1) * 64, wn = (wave & 1) * 64;
    f32x4 acc[4][4];
#pragma unroll
    for (int i = 0; i < 4; i++)
#pragma unroll
        for (int j = 0; j < 4; j++) acc[i][j] = (f32x4){0.f, 0.f, 0.f, 0.f};
    int sr = wave * 32 + (lane >> 2);
    int sc = (lane & 3) * 8;
    const int fr = lane & 15;
    const int fk = (lane >> 4) * 8;
    const unsigned short* APs[3] = {h2h, h2h, h2l};
    const unsigned short* BPs[3] = {MTh, MTl, MTh};
    for (int it = 0; it < 12; it++) {
        int ph = it >> 2, k0 = (it & 3) * 32;
        const unsigned short* ga = APs[ph] + (size_t)(bm + sr) * 128 + k0 + sc;
        gl_lds16(ga, &sA[sr * 32 + sc]);
        gl_lds16(ga + 16 * 128, &sA[(sr + 16) * 32 + sc]);
        const unsigned short* gb = BPs[ph] + (size_t)sr * 128 + k0 + sc;
        gl_lds16(gb, &sB[sr * 32 + sc]);
        gl_lds16(gb + 16 * 128, &sB[(sr + 16) * 32 + sc]);
        __syncthreads();
        bf16x8 af[4], bfr[4];
#pragma unroll
        for (int i = 0; i < 4; i++) af[i] = *(const bf16x8*)&sA[(wm + i * 16 + fr) * 32 + fk];
#pragma unroll
        for (int j = 0; j < 4; j++) bfr[j] = *(const bf16x8*)&sB[(wn + j * 16 + fr) * 32 + fk];
#pragma unroll
        for (int i = 0; i < 4; i++)
#pragma unroll
            for (int j = 0; j < 4; j++)
                acc[i][j] = __builtin_amdgcn_mfma_f32_16x16x32_bf16(af[i], bfr[j], acc[i][j], 0, 0, 0);
        __syncthreads();
    }
    int rq = (lane >> 4) * 4;
#pragma unroll
    for (int i = 0; i < 4; i++)
#pragma unroll
        for (int j = 0; j < 4; j++) {
            int col = wn + j * 16 + fr;
#pragma unroll
            for (int r = 0; r < 4; r++) {
                int row = bm + wm + i * 16 + rq + r;
                float v = acc[i][j][r];
                unsigned short h = f2bf(v);
                Th[(size_t)row * 128 + col] = h;
                Tl[(size_t)row * 128 + col] = f2bf(v - bf2f(h));
            }
        }
}

// ---------------- aggregation, 512-dim (pre-scaled rows), +bias, relu, bf16 out ----------------
// t rows are pre-scaled by invs[row]; out = relu(invs[node]*(sum_edges + self) + bias)
__global__ __launch_bounds__(256) void agg512(const unsigned short* t, const int* rowptr,
                                              const int* colv, const float* invs,
                                              const float* bias, unsigned short* outp) {
    int wave = threadIdx.x >> 6, lane = threadIdx.x & 63;
    int node = blockIdx.x * 4 + wave;
    int d0 = lane * 8;
    float acc[8] = {0.f, 0.f, 0.f, 0.f, 0.f, 0.f, 0.f, 0.f};
    int r0 = rowptr[node], r1 = rowptr[node + 1];
    // self row + scale issued early (independent of edge loop)
    uint4 sv = *(const uint4*)&t[(size_t)node * 512 + d0];
    float wd = invs[node];
    int e = r0;
    for (; e + 8 <= r1; e += 8) {           // 8 rows in flight
        int s[8];
#pragma unroll
        for (int c = 0; c < 8; c++) s[c] = colv[e + c];
        uint4 v[8];
#pragma unroll
        for (int c = 0; c < 8; c++) v[c] = *(const uint4*)&t[(size_t)s[c] * 512 + d0];
#pragma unroll
        for (int c = 0; c < 8; c++) {
            acc[0] += blo(v[c].x); acc[1] += bhi(v[c].x);
            acc[2] += blo(v[c].y); acc[3] += bhi(v[c].y);
            acc[4] += blo(v[c].z); acc[5] += bhi(v[c].z);
            acc[6] += blo(v[c].w); acc[7] += bhi(v[c].w);
        }
    }
    if (e + 4 <= r1) {                      // 4-chain middle
        int s[4];
#pragma unroll
        for (int c = 0; c < 4; c++) s[c] = colv[e + c];
        uint4 v[4];
#pragma unroll
        for (int c = 0; c < 4; c++) v[c] = *(const uint4*)&t[(size_t)s[c] * 512 + d0];
#pragma unroll
        for (int c = 0; c < 4; c++) {
            acc[0] += blo(v[c].x); acc[1] += bhi(v[c].x);
            acc[2] += blo(v[c].y); acc[3] += bhi(v[c].y);
            acc[4] += blo(v[c].z); acc[5] += bhi(v[c].z);
            acc[6] += blo(v[c].w); acc[7] += bhi(v[c].w);
        }
        e += 4;
    }
    for (; e < r1; e++) {
        uint4 v = *(const uint4*)&t[(size_t)colv[e] * 512 + d0];
        acc[0] += blo(v.x); acc[1] += bhi(v.x);
        acc[2] += blo(v.y); acc[3] += bhi(v.y);
        acc[4] += blo(v.z); acc[5] += bhi(v.z);
        acc[6] += blo(v.w); acc[7] += bhi(v.w);
    }
    acc[0] += blo(sv.x); acc[1] += bhi(sv.x);
    acc[2] += blo(sv.y); acc[3] += bhi(sv.y);
    acc[4] += blo(sv.z); acc[5] += bhi(sv.z);
    acc[6] += blo(sv.w); acc[7] += bhi(sv.w);
    float o[8];
#pragma unroll
    for (int k = 0; k < 8; k++) {
        float v = acc[k] * wd + bias[d0 + k];
        o[k] = v > 0.f ? v : 0.f;
    }
    uint4 pv;
    pv.x = pack2(o[0], o[1]); pv.y = pack2(o[2], o[3]);
    pv.z = pack2(o[4], o[5]); pv.w = pack2(o[6], o[7]);
    *(uint4*)&outp[(size_t)node * 512 + d0] = pv;
}

// ---------------- aggregation, 128-dim (pre-scaled rows), +bias, hi/lo split out ----------------
__global__ __launch_bounds__(256) void agg128(const unsigned short* u, const int* rowptr,
                                              const int* colv, const float* invs,
                                              const float* bias, unsigned short* h2h, unsigned short* h2l) {
    int wave = threadIdx.x >> 6, lane = threadIdx.x & 63;
    int node = blockIdx.x * 4 + wave;
    int q = lane >> 4, ql = lane & 15;
    int d0 = ql * 8;
    float acc[8] = {0.f, 0.f, 0.f, 0.f, 0.f, 0.f, 0.f, 0.f};
    int r0 = rowptr[node], r1 = rowptr[node + 1];
    uint4 sv = *(const uint4*)&u[(size_t)node * 128 + d0];
    float wd = invs[node];
    int e = r0 + q;
    for (; e + 4 < r1; e += 8) {            // 2 rows in flight per q-group (8/wave)
        int s0 = colv[e], s1 = colv[e + 4];
        uint4 v0 = *(const uint4*)&u[(size_t)s0 * 128 + d0];
        uint4 v1 = *(const uint4*)&u[(size_t)s1 * 128 + d0];
        acc[0] += blo(v0.x) + blo(v1.x); acc[1] += bhi(v0.x) + bhi(v1.x);
        acc[2] += blo(v0.y) + blo(v1.y); acc[3] += bhi(v0.y) + bhi(v1.y);
        acc[4] += blo(v0.z) + blo(v1.z); acc[5] += bhi(v0.z) + bhi(v1.z);
        acc[6] += blo(v0.w) + blo(v1.w); acc[7] += bhi(v0.w) + bhi(v1.w);
    }
    if (e < r1) {
        uint4 v = *(const uint4*)&u[(size_t)colv[e] * 128 + d0];
        acc[0] += blo(v.x); acc[1] += bhi(v.x);
        acc[2] += blo(v.y); acc[3] += bhi(v.y);
        acc[4] += blo(v.z); acc[5] += bhi(v.z);
        acc[6] += blo(v.w); acc[7] += bhi(v.w);
    }
#pragma unroll
    for (int k = 0; k < 8; k++) {
        acc[k] += __shfl_xor(acc[k], 16);
        acc[k] += __shfl_xor(acc[k], 32);
    }
    float sf[8] = {blo(sv.x), bhi(sv.x), blo(sv.y), bhi(sv.y), blo(sv.z), bhi(sv.z), blo(sv.w), bhi(sv.w)};
    unsigned short hh[8], hl[8];
#pragma unroll
    for (int k = 0; k < 8; k++) {
        float v = (acc[k] + sf[k]) * wd + bias[d0 + k];
        hh[k] = f2bf(v);
        hl[k] = f2bf(v - bf2f(hh[k]));
    }
    if (q == 0) {
        uint4 ph, pl;
        ph.x = ((unsigned)hh[1] << 16) | hh[0]; ph.y = ((unsigned)hh[3] << 16) | hh[2];
        ph.z = ((unsigned)hh[5] << 16) | hh[4]; ph.w = ((unsigned)hh[7] << 16) | hh[6];
        pl.x = ((unsigned)hl[1] << 16) | hl[0]; pl.y = ((unsigned)hl[3] << 16) | hl[2];
        pl.z = ((unsigned)hl[5] << 16) | hl[4]; pl.w = ((unsigned)hl[7] << 16) | hl[6];
        *(uint4*)&h2h[(size_t)node * 128 + d0] = ph;
        *(uint4*)&h2l[(size_t)node * 128 + d0] = pl;
    }
}

// ---------------- bilinear: s = T @ e^T, out = s*w + b ----------------
__global__ __launch_bounds__(256, 2) void bilinear_k(const unsigned short* Th, const unsigned short* Tl,
                                                     const unsigned short* Eh, const float* lin_w,
                                                     const float* lin_b, float* outp) {
    int tid = threadIdx.x, wave = tid >> 6, lane = tid & 63;
    int b = blockIdx.x >> 1, half = blockIdx.x & 1;
    int fr = lane & 15, q = lane >> 4;
    int irow0 = b * 256 + half * 128 + wave * 32;
    bf16x8 Ah[2][4], Al[2][4];
#pragma unroll
    for (int it = 0; it < 2; it++)
#pragma unroll
        for (int kk = 0; kk < 4; kk++) {
            size_t off = (size_t)(irow0 + it * 16 + fr) * 128 + kk * 32 + q * 8;
            Ah[it][kk] = *(const bf16x8*)&Th[off];
            Al[it][kk] = *(const bf16x8*)&Tl[off];
        }
    float w0 = lin_w[0], w1 = lin_w[1], c0 = lin_b[0], c1 = lin_b[1];
    for (int jt = 0; jt < 16; jt++) {
        bf16x8 Bf[4];
#pragma unroll
        for (int kk = 0; kk < 4; kk++)
            Bf[kk] = *(const bf16x8*)&Eh[(size_t)(b * 256 + jt * 16 + fr) * 128 + kk * 32 + q * 8];
#pragma unroll
        for (int it = 0; it < 2; it++) {
            f32x4 acc = (f32x4){0.f, 0.f, 0.f, 0.f};
#pragma unroll
            for (int kk = 0; kk < 4; kk++) {
                acc = __builtin_amdgcn_mfma_f32_16x16x32_bf16(Ah[it][kk], Bf[kk], acc, 0, 0, 0);
                acc = __builtin_amdgcn_mfma_f32_16x16x32_bf16(Al[it][kk], Bf[kk], acc, 0, 0, 0);
            }
#pragma unroll
            for (int r = 0; r < 4; r++) {
                int iloc = half * 128 + wave * 32 + it * 16 + q * 4 + r;
                int jloc = jt * 16 + fr;
                size_t o = ((size_t)b * 65536 + (size_t)iloc * 256 + jloc) * 2;
                float s = acc[r];
                float2 ov;
                ov.x = fmaf(s, w0, c0);
                ov.y = fmaf(s, w1, c1);
                *(float2*)&outp[o] = ov;
            }
        }
    }
}

extern "C" void kernel_launch(void* const* d_in, const int* in_sizes, int n_in,
                              void* d_out, int out_size, void* d_ws, size_t ws_size,
                              hipStream_t stream) {
    const float* x   = (const float*)d_in[0];
    const float* Wt1 = (const float*)d_in[1];
    const float* bt1 = (const float*)d_in[2];
    const float* Wt2 = (const float*)d_in[3];
    const float* bt2 = (const float*)d_in[4];
    const float* W1  = (const float*)d_in[5];
    const float* b1  = (const float*)d_in[6];
    const float* W2  = (const float*)d_in[7];
    const float* b2  = (const float*)d_in[8];
    const float* Mtx = (const float*)d_in[9];
    const float* lw  = (const float*)d_in[10];
    const float* lb  = (const float*)d_in[11];
    const int*   ei  = (const int*)d_in[12];
    int E = in_sizes[12] / 2;
    const int* srcp = ei;
    const int* dstp = ei + E;

    unsigned char* p = (unsigned char*)d_ws;
    size_t off = 0;
    auto alloc = [&](size_t bytes) -> void* {
        void* r = p + off;
        off = (off + bytes + 255) & ~(size_t)255;
        return r;
    };
    int*   cnt    = (int*)alloc((size_t)NN * 4);
    int*   rowptr = (int*)alloc(((size_t)NN + 1) * 4);
    int*   cursor = (int*)alloc((size_t)NN * 4);
    float* invs   = (float*)alloc((size_t)NN * 4);
    int*   bsum   = (int*)alloc(256 * 4);
    int*   boff   = (int*)alloc(256 * 4);
    int*   colv   = (int*)alloc((size_t)E * 4);
    unsigned short* Wcat   = (unsigned short*)alloc(524288 * 2);
    unsigned short* W1T    = (unsigned short*)alloc(262144 * 2);
    unsigned short* W2T    = (unsigned short*)alloc(65536 * 2);
    unsigned short* MTh    = (unsigned short*)alloc(16384 * 2);
    unsigned short* MTl    = (unsigned short*)alloc(16384 * 2);
    float*          cbias  = (float*)alloc(512 * 4);
    unsigned short* WcombT = (unsigned short*)alloc(524288 * 2);
    unsigned short* t1     = (unsigned short*)alloc((size_t)NN * 512 * 2);
    unsigned short* h1     = (unsigned short*)alloc((size_t)NN * 512 * 2);
    unsigned short* uu     = (unsigned short*)alloc((size_t)NN * 128 * 2);
    // aliases (lifetimes disjoint): T over t1, h2 over h1
    unsigned short* Th  = t1;
    unsigned short* Tl  = t1 + (size_t)NN * 128;
    unsigned short* h2h = h1;
    unsigned short* h2l = h1 + (size_t)NN * 128;

    hipMemsetAsync(cnt, 0, (size_t)NN * 4, stream);
    prep_pack<<<3392, 256, 0, stream>>>(Wt1, Wt2, W1, W2, Mtx, Wcat, W1T, W2T, MTh, MTl);
    cbias_k<<<16, 256, 0, stream>>>(bt1, bt2, W1, cbias);
    count_k<<<(E + 255) / 256, 256, 0, stream>>>(dstp, cnt, E);
    red_k<<<256, 256, 0, stream>>>(cnt, bsum);
    scanb_k<<<1, 256, 0, stream>>>(bsum, boff);
    scanf_k<<<256, 256, 0, stream>>>(cnt, boff, rowptr, cursor, invs);
    fill_k<<<(E + 255) / 256, 256, 0, stream>>>(srcp, dstp, cursor, colv, E);
    // WcombT[512][1024] = (Wcat @ W1)^T = W1T @ Wcat^T
    gemm_bt<<<dim3(8, 4), 256, 0, stream>>>(W1T, Wcat, WcombT, nullptr, nullptr, 512, 1024, 512);
    // t1 = (x @ Wcomb + cbias) * invs[row]   [65536,512]
    gemm_f32a<<<2048, 256, 0, stream>>>(x, WcombT, t1, cbias, invs);
    // h1 = relu(invs*(sum + self) + b1)
    agg512<<<NN / 4, 256, 0, stream>>>(t1, rowptr, colv, invs, b1, h1);
    // u = (h1 @ W2) * invs[row]   [65536,128]
    gemm_bt<<<dim3(1, 512), 256, 0, stream>>>(h1, W2T, uu, nullptr, invs, NN, 128, 512);
    // h2 = invs*(sum + self) + b2 (hi/lo split)
    agg128<<<NN / 4, 256, 0, stream>>>(uu, rowptr, colv, invs, b2, h2h, h2l);
    // T = h2 @ M (split)
    gemm_T<<<512, 256, 0, stream>>>(h2h, h2l, MTh, MTl, Th, Tl);
    // scores + Linear(1,2)
    bilinear_k<<<512, 256, 0, stream>>>(Th, Tl, h2h, lw, lb, (float*)d_out);
}

// Round 4
// 911.227 us; speedup vs baseline: 1.0209x; 1.0209x over previous
//
#include <hip/hip_runtime.h>
#include <stdint.h>

#define NN 65536

typedef __attribute__((ext_vector_type(8))) short bf16x8;
typedef __attribute__((ext_vector_type(4))) float f32x4;

__device__ __forceinline__ unsigned short f2bf(float f) {
    unsigned u = __float_as_uint(f);
    u += 0x7fffu + ((u >> 16) & 1u);
    return (unsigned short)(u >> 16);
}
__device__ __forceinline__ float bf2f(unsigned short h) { return __uint_as_float(((unsigned)h) << 16); }
__device__ __forceinline__ float blo(unsigned u) { return __uint_as_float(u << 16); }
__device__ __forceinline__ float bhi(unsigned u) { return __uint_as_float(u & 0xffff0000u); }
__device__ __forceinline__ unsigned pack2(float a, float b) {
    return ((unsigned)f2bf(b) << 16) | (unsigned)f2bf(a);
}
// lo16 = hi16(x) [trunc-to-bf16], hi16 = hi16(y)
__device__ __forceinline__ unsigned trunc2(float x, float y) {
    return __builtin_amdgcn_perm(__float_as_uint(y), __float_as_uint(x), 0x07060302u);
}

__device__ __forceinline__ void gl_lds16(const void* g, void* l) {
    __builtin_amdgcn_global_load_lds((const __attribute__((address_space(1))) void*)g,
                                     (__attribute__((address_space(3))) void*)l, 16, 0, 0);
}

// ---------------- prep: pack/transpose weights to bf16 ----------------
__global__ void prep_pack(const float* Wt1, const float* Wt2, const float* W1,
                          const float* W2, const float* Mtx,
                          unsigned short* Wcat, unsigned short* W1T,
                          unsigned short* W2T, unsigned short* MTh, unsigned short* MTl) {
    int i = blockIdx.x * 256 + threadIdx.x;
    if (i < 524288) {                       // Wcat [1024][512]
        int k = i >> 9, j = i & 511;
        float v = (k < 256) ? Wt1[k * 512 + j] : Wt2[(k - 256) * 512 + j];
        Wcat[i] = f2bf(v);
    } else if (i < 786432) {                // W1T [512][512]
        int t = i - 524288; int n = t >> 9, j = t & 511;
        W1T[t] = f2bf(W1[j * 512 + n]);
    } else if (i < 851968) {                // W2T [128][512]
        int t = i - 786432; int n = t >> 9, j = t & 511;
        W2T[t] = f2bf(W2[j * 128 + n]);
    } else if (i < 868352) {                // MT [128][128] hi/lo, MT[r][c]=M[c][r]
        int t = i - 851968; int d = t >> 7, e = t & 127;
        float m = Mtx[e * 128 + d];
        unsigned short h = f2bf(m);
        MTh[t] = h; MTl[t] = f2bf(m - bf2f(h));
    }
}

// cbias = (bt1+bt2) @ W1 — 16 blocks, K-partitioned reduction
__global__ void cbias_k(const float* bt1, const float* bt2, const float* W1, float* c) {
    __shared__ float sm[256];
    int t = threadIdx.x;
    int n = blockIdx.x * 32 + (t & 31);
    int jp = t >> 5;                        // 8 K-partitions of 64
    float acc = 0.f;
    for (int j = jp * 64; j < jp * 64 + 64; j++)
        acc += (bt1[j] + bt2[j]) * W1[j * 512 + n];
    sm[t] = acc;
    __syncthreads();
    if (t < 32) {
        float a = 0.f;
#pragma unroll
        for (int p = 0; p < 8; p++) a += sm[p * 32 + t];
        c[blockIdx.x * 32 + t] = a;
    }
}

// ---------------- CSR build ----------------
__global__ void count_k(const int* dst, int* cnt, int E) {
    int e = blockIdx.x * 256 + threadIdx.x;
    if (e < E) atomicAdd(&cnt[dst[e]], 1);
}
__global__ void red_k(const int* cnt, int* bsum) {
    __shared__ int sm[256];
    int tid = threadIdx.x;
    sm[tid] = cnt[blockIdx.x * 256 + tid];
    __syncthreads();
    for (int s = 128; s > 0; s >>= 1) {
        if (tid < s) sm[tid] += sm[tid + s];
        __syncthreads();
    }
    if (tid == 0) bsum[blockIdx.x] = sm[0];
}
__global__ void scanb_k(const int* bsum, int* boff) {
    __shared__ int sm[256];
    int tid = threadIdx.x;
    int v0 = bsum[tid];
    sm[tid] = v0;
    __syncthreads();
    for (int s = 1; s < 256; s <<= 1) {
        int t = sm[tid];
        if (tid >= s) t += sm[tid - s];
        __syncthreads();
        sm[tid] = t;
        __syncthreads();
    }
    boff[tid] = sm[tid] - v0;   // exclusive
}
__global__ void scanf_k(const int* cnt, const int* boff, int* rowptr, int* cursor, float* invs) {
    __shared__ int sm[256];
    int tid = threadIdx.x;
    int i = blockIdx.x * 256 + tid;
    int v = cnt[i];
    sm[tid] = v;
    __syncthreads();
    for (int s = 1; s < 256; s <<= 1) {
        int t = sm[tid];
        if (tid >= s) t += sm[tid - s];
        __syncthreads();
        sm[tid] = t;
        __syncthreads();
    }
    int incl = sm[tid];
    int base = boff[blockIdx.x];
    int excl = base + incl - v;
    rowptr[i] = excl;
    cursor[i] = excl;
    invs[i] = rsqrtf((float)(v + 1));
    if (i == NN - 1) rowptr[NN] = base + incl;
}
__global__ void fill_k(const int* src, const int* dst, int* cursor, int* colv, int E) {
    int e = blockIdx.x * 256 + threadIdx.x;
    if (e < E) {
        int d = dst[e];
        int p = atomicAdd(&cursor[d], 1);
        colv[p] = src[e];
    }
}

// ---------------- generic bf16 GEMM: C[M,N] = A[M,K] @ BT[N,K]^T (+bias[col]) * rs[row] ----------------
// LDS tiles XOR-swizzled: 16B chunk c of row r lives at phys slot c^((r>>1)&3).
// Staged via gl_lds with pre-swizzled GLOBAL source (LDS dest linear); reads use
// fk2. Both XOR terms collapse to per-thread constants (rows differ by mult. of 16).
__global__ __launch_bounds__(256, 2) void gemm_bt(const unsigned short* A, const unsigned short* BT,
                                                  unsigned short* C, const float* bias,
                                                  const float* rs,
                                                  int M, int N, int K) {
    __shared__ __align__(16) unsigned short sA[128 * 32];
    __shared__ __align__(16) unsigned short sB[128 * 32];
    int tid = threadIdx.x, wave = tid >> 6, lane = tid & 63;
    int bm = blockIdx.y * 128, bn = blockIdx.x * 128;
    int wm = (wave >> 1) * 64, wn = (wave & 1) * 64;
    f32x4 acc[4][4];
#pragma unroll
    for (int i = 0; i < 4; i++)
#pragma unroll
        for (int j = 0; j < 4; j++) acc[i][j] = (f32x4){0.f, 0.f, 0.f, 0.f};
    int sr = wave * 32 + (lane >> 2);
    int sc = (lane & 3) * 8;                               // linear LDS dest column
    int ssc = (((lane & 3) ^ ((lane >> 3) & 3))) * 8;      // swizzled global source column
    const int fr = lane & 15;
    const int fk2 = (((lane >> 4) ^ ((lane >> 1) & 3))) * 8;  // swizzled fragment offset
    for (int k0 = 0; k0 < K; k0 += 32) {
        const unsigned short* ga = A + (size_t)(bm + sr) * K + k0 + ssc;
        gl_lds16(ga, &sA[sr * 32 + sc]);
        gl_lds16(ga + (size_t)16 * K, &sA[(sr + 16) * 32 + sc]);
        const unsigned short* gb = BT + (size_t)(bn + sr) * K + k0 + ssc;
        gl_lds16(gb, &sB[sr * 32 + sc]);
        gl_lds16(gb + (size_t)16 * K, &sB[(sr + 16) * 32 + sc]);
        __syncthreads();
        bf16x8 af[4], bfr[4];
#pragma unroll
        for (int i = 0; i < 4; i++) af[i] = *(const bf16x8*)&sA[(wm + i * 16 + fr) * 32 + fk2];
#pragma unroll
        for (int j = 0; j < 4; j++) bfr[j] = *(const bf16x8*)&sB[(wn + j * 16 + fr) * 32 + fk2];
#pragma unroll
        for (int i = 0; i < 4; i++)
#pragma unroll
            for (int j = 0; j < 4; j++)
                acc[i][j] = __builtin_amdgcn_mfma_f32_16x16x32_bf16(af[i], bfr[j], acc[i][j], 0, 0, 0);
        __syncthreads();
    }
    int rq = (lane >> 4) * 4;
#pragma unroll
    for (int i = 0; i < 4; i++)
#pragma unroll
        for (int j = 0; j < 4; j++) {
            int col = bn + wn + j * 16 + fr;
            float bb = bias ? bias[col] : 0.f;
#pragma unroll
            for (int r = 0; r < 4; r++) {
                int row = bm + wm + i * 16 + rq + r;
                float scale = rs ? rs[row] : 1.f;
                C[(size_t)row * N + col] = f2bf((acc[i][j][r] + bb) * scale);
            }
        }
}

// ---------------- GEMM1: t1 = x[65536,1024] @ WcombT^T + cbias, row-scaled by invs ----------------
// m97 2-barrier structure. A stays fp32 in LDS via gl_lds with its own XOR swizzle
// (conflict-free, verified). B tile now also XOR-swizzled (pre-swizzled source +
// fk2 read) — removes the 4x bank-quad collision on B ds_read_b128 that produced
// the constant 1.26e7 SQ_LDS_BANK_CONFLICT.
__global__ __launch_bounds__(256, 2) void gemm_f32a(const float* A, const unsigned short* BT,
                                                    unsigned short* C, const float* bias,
                                                    const float* rs) {
    const int K = 1024, N = 512;
    __shared__ __align__(16) float sAf[128 * 32];          // 16 KB
    __shared__ __align__(16) unsigned short sB[128 * 32];  // 8 KB
    int tid = threadIdx.x, wave = tid >> 6, lane = tid & 63;
    int b = blockIdx.x;
    int xcd = b & 7, jn = (b >> 3) & 3, tt = b >> 5;
    int bm = (tt * 8 + xcd) * 128, bn = jn * 128;
    int wm = (wave >> 1) * 64, wn = (wave & 1) * 64;
    f32x4 acc[4][4];
#pragma unroll
    for (int i = 0; i < 4; i++)
#pragma unroll
        for (int j = 0; j < 4; j++) acc[i][j] = (f32x4){0.f, 0.f, 0.f, 0.f};
    // B staging: linear dest, swizzled source
    int sr = wave * 32 + (lane >> 2);
    int sc = (lane & 3) * 8;
    int ssc = (((lane & 3) ^ ((lane >> 3) & 3))) * 8;
    // A staging: per wave 4 DMA instrs, instr i covers rows wave*32+i*8 .. +7;
    // lane L -> row (L>>3), LDS chunk-slot (L&7); source global chunk = slot ^ (row&7)
    int arow = lane >> 3;                    // 0..7
    int achk = (lane & 7) ^ arow;            // swizzled source chunk
    const int fr = lane & 15;
    const int fk = (lane >> 4) * 8;
    const int fk2 = (((lane >> 4) ^ ((lane >> 1) & 3))) * 8;
    const float* Abase = A + (size_t)(bm + wave * 32 + arow) * K + achk * 4;
    const unsigned short* Bbase = BT + (size_t)(bn + sr) * K + ssc;
    for (int k0 = 0; k0 < K; k0 += 32) {
#pragma unroll
        for (int i = 0; i < 4; i++)
            gl_lds16(Abase + (size_t)(8 * i) * K + k0, &sAf[(wave * 32 + i * 8) * 32]);
        gl_lds16(Bbase + k0, &sB[sr * 32 + sc]);
        gl_lds16(Bbase + (size_t)16 * K + k0, &sB[(sr + 16) * 32 + sc]);
        __syncthreads();
        bf16x8 af[4], bfr[4];
#pragma unroll
        for (int i = 0; i < 4; i++) {
            int r = wm + i * 16 + fr;
            int s = r & 7;
            int c0 = fk >> 2;
            float4 fa = *(const float4*)&sAf[r * 32 + ((c0 ^ s) << 2)];
            float4 fb = *(const float4*)&sAf[r * 32 + (((c0 + 1) ^ s) << 2)];
            union { unsigned u[4]; bf16x8 v; } t;
            t.u[0] = trunc2(fa.x, fa.y);
            t.u[1] = trunc2(fa.z, fa.w);
            t.u[2] = trunc2(fb.x, fb.y);
            t.u[3] = trunc2(fb.z, fb.w);
            af[i] = t.v;
        }
#pragma unroll
        for (int j = 0; j < 4; j++) bfr[j] = *(const bf16x8*)&sB[(wn + j * 16 + fr) * 32 + fk2];
#pragma unroll
        for (int i = 0; i < 4; i++)
#pragma unroll
            for (int j = 0; j < 4; j++)
                acc[i][j] = __builtin_amdgcn_mfma_f32_16x16x32_bf16(af[i], bfr[j], acc[i][j], 0, 0, 0);
        __syncthreads();
    }
    int rq = (lane >> 4) * 4;
#pragma unroll
    for (int i = 0; i < 4; i++)
#pragma unroll
        for (int j = 0; j < 4; j++) {
            int col = bn + wn + j * 16 + fr;
            float bb = bias[col];
#pragma unroll
            for (int r = 0; r < 4; r++) {
                int row = bm + wm + i * 16 + rq + r;
                C[(size_t)row * N + col] = f2bf((acc[i][j][r] + bb) * rs[row]);
            }
        }
}

// ---------------- T = h2 @ M with hi/lo split (3 phases), split output ----------------
__global__ __launch_bounds__(256, 2) void gemm_T(const unsigned short* h2h, const unsigned short* h2l,
                                                 const unsigned short* MTh, const unsigned short* MTl,
                                                 unsigned short* Th, unsigned short* Tl) {
    __shared__ __align__(16) unsigned short sA[128 * 32];
    __shared__ __align__(16) unsigned short sB[128 * 32];
    int tid = threadIdx.x, wave = tid >> 6, lane = tid & 63;
    int bm = blockIdx.x * 128;
    int wm = (wave >> 1) * 64, wn = (wave & 1) * 64;
    f32x4 acc[4][4];
#pragma unroll
    for (int i = 0; i < 4; i++)
#pragma unroll
        for (int j = 0; j < 4; j++) acc[i][j] = (f32x4){0.f, 0.f, 0.f, 0.f};
    int sr = wave * 32 + (lane >> 2);
    int sc = (lane & 3) * 8;
    int ssc = (((lane & 3) ^ ((lane >> 3) & 3))) * 8;
    const int fr = lane & 15;
    const int fk2 = (((lane >> 4) ^ ((lane >> 1) & 3))) * 8;
    const unsigned short* APs[3] = {h2h, h2h, h2l};
    const unsigned short* BPs[3] = {MTh, MTl, MTh};
    for (int it = 0; it < 12; it++) {
        int ph = it >> 2, k0 = (it & 3) * 32;
        const unsigned short* ga = APs[ph] + (size_t)(bm + sr) * 128 + k0 + ssc;
        gl_lds16(ga, &sA[sr * 32 + sc]);
        gl_lds16(ga + 16 * 128, &sA[(sr + 16) * 32 + sc]);
        const unsigned short* gb = BPs[ph] + (size_t)sr * 128 + k0 + ssc;
        gl_lds16(gb, &sB[sr * 32 + sc]);
        gl_lds16(gb + 16 * 128, &sB[(sr + 16) * 32 + sc]);
        __syncthreads();
        bf16x8 af[4], bfr[4];
#pragma unroll
        for (int i = 0; i < 4; i++) af[i] = *(const bf16x8*)&sA[(wm + i * 16 + fr) * 32 + fk2];
#pragma unroll
        for (int j = 0; j < 4; j++) bfr[j] = *(const bf16x8*)&sB[(wn + j * 16 + fr) * 32 + fk2];
#pragma unroll
        for (int i = 0; i < 4; i++)
#pragma unroll
            for (int j = 0; j < 4; j++)
                acc[i][j] = __builtin_amdgcn_mfma_f32_16x16x32_bf16(af[i], bfr[j], acc[i][j], 0, 0, 0);
        __syncthreads();
    }
    int rq = (lane >> 4) * 4;
#pragma unroll
    for (int i = 0; i < 4; i++)
#pragma unroll
        for (int j = 0; j < 4; j++) {
            int col = wn + j * 16 + fr;
#pragma unroll
            for (int r = 0; r < 4; r++) {
                int row = bm + wm + i * 16 + rq + r;
                float v = acc[i][j][r];
                unsigned short h = f2bf(v);
                Th[(size_t)row * 128 + col] = h;
                Tl[(size_t)row * 128 + col] = f2bf(v - bf2f(h));
            }
        }
}

// ---------------- aggregation, 512-dim (pre-scaled rows), +bias, relu, bf16 out ----------------
// t rows are pre-scaled by invs[row]; out = relu(invs[node]*(sum_edges + self) + bias)
__global__ __launch_bounds__(256) void agg512(const unsigned short* t, const int* rowptr,
                                              const int* colv, const float* invs,
                                              const float* bias, unsigned short* outp) {
    int wave = threadIdx.x >> 6, lane = threadIdx.x & 63;
    int node = blockIdx.x * 4 + wave;
    int d0 = lane * 8;
    float acc[8] = {0.f, 0.f, 0.f, 0.f, 0.f, 0.f, 0.f, 0.f};
    int r0 = rowptr[node], r1 = rowptr[node + 1];
    // self row + scale issued early (independent of edge loop)
    uint4 sv = *(const uint4*)&t[(size_t)node * 512 + d0];
    float wd = invs[node];
    int e = r0;
    for (; e + 8 <= r1; e += 8) {           // 8 rows in flight
        int s[8];
#pragma unroll
        for (int c = 0; c < 8; c++) s[c] = colv[e + c];
        uint4 v[8];
#pragma unroll
        for (int c = 0; c < 8; c++) v[c] = *(const uint4*)&t[(size_t)s[c] * 512 + d0];
#pragma unroll
        for (int c = 0; c < 8; c++) {
            acc[0] += blo(v[c].x); acc[1] += bhi(v[c].x);
            acc[2] += blo(v[c].y); acc[3] += bhi(v[c].y);
            acc[4] += blo(v[c].z); acc[5] += bhi(v[c].z);
            acc[6] += blo(v[c].w); acc[7] += bhi(v[c].w);
        }
    }
    if (e + 4 <= r1) {                      // 4-chain middle
        int s[4];
#pragma unroll
        for (int c = 0; c < 4; c++) s[c] = colv[e + c];
        uint4 v[4];
#pragma unroll
        for (int c = 0; c < 4; c++) v[c] = *(const uint4*)&t[(size_t)s[c] * 512 + d0];
#pragma unroll
        for (int c = 0; c < 4; c++) {
            acc[0] += blo(v[c].x); acc[1] += bhi(v[c].x);
            acc[2] += blo(v[c].y); acc[3] += bhi(v[c].y);
            acc[4] += blo(v[c].z); acc[5] += bhi(v[c].z);
            acc[6] += blo(v[c].w); acc[7] += bhi(v[c].w);
        }
        e += 4;
    }
    for (; e < r1; e++) {
        uint4 v = *(const uint4*)&t[(size_t)colv[e] * 512 + d0];
        acc[0] += blo(v.x); acc[1] += bhi(v.x);
        acc[2] += blo(v.y); acc[3] += bhi(v.y);
        acc[4] += blo(v.z); acc[5] += bhi(v.z);
        acc[6] += blo(v.w); acc[7] += bhi(v.w);
    }
    acc[0] += blo(sv.x); acc[1] += bhi(sv.x);
    acc[2] += blo(sv.y); acc[3] += bhi(sv.y);
    acc[4] += blo(sv.z); acc[5] += bhi(sv.z);
    acc[6] += blo(sv.w); acc[7] += bhi(sv.w);
    float o[8];
#pragma unroll
    for (int k = 0; k < 8; k++) {
        float v = acc[k] * wd + bias[d0 + k];
        o[k] = v > 0.f ? v : 0.f;
    }
    uint4 pv;
    pv.x = pack2(o[0], o[1]); pv.y = pack2(o[2], o[3]);
    pv.z = pack2(o[4], o[5]); pv.w = pack2(o[6], o[7]);
    *(uint4*)&outp[(size_t)node * 512 + d0] = pv;
}

// ---------------- aggregation, 128-dim (pre-scaled rows), +bias, hi/lo split out ----------------
__global__ __launch_bounds__(256) void agg128(const unsigned short* u, const int* rowptr,
                                              const int* colv, const float* invs,
                                              const float* bias, unsigned short* h2h, unsigned short* h2l) {
    int wave = threadIdx.x >> 6, lane = threadIdx.x & 63;
    int node = blockIdx.x * 4 + wave;
    int q = lane >> 4, ql = lane & 15;
    int d0 = ql * 8;
    float acc[8] = {0.f, 0.f, 0.f, 0.f, 0.f, 0.f, 0.f, 0.f};
    int r0 = rowptr[node], r1 = rowptr[node + 1];
    uint4 sv = *(const uint4*)&u[(size_t)node * 128 + d0];
    float wd = invs[node];
    int e = r0 + q;
    for (; e + 4 < r1; e += 8) {            // 2 rows in flight per q-group (8/wave)
        int s0 = colv[e], s1 = colv[e + 4];
        uint4 v0 = *(const uint4*)&u[(size_t)s0 * 128 + d0];
        uint4 v1 = *(const uint4*)&u[(size_t)s1 * 128 + d0];
        acc[0] += blo(v0.x) + blo(v1.x); acc[1] += bhi(v0.x) + bhi(v1.x);
        acc[2] += blo(v0.y) + blo(v1.y); acc[3] += bhi(v0.y) + bhi(v1.y);
        acc[4] += blo(v0.z) + blo(v1.z); acc[5] += bhi(v0.z) + bhi(v1.z);
        acc[6] += blo(v0.w) + blo(v1.w); acc[7] += bhi(v0.w) + bhi(v1.w);
    }
    if (e < r1) {
        uint4 v = *(const uint4*)&u[(size_t)colv[e] * 128 + d0];
        acc[0] += blo(v.x); acc[1] += bhi(v.x);
        acc[2] += blo(v.y); acc[3] += bhi(v.y);
        acc[4] += blo(v.z); acc[5] += bhi(v.z);
        acc[6] += blo(v.w); acc[7] += bhi(v.w);
    }
#pragma unroll
    for (int k = 0; k < 8; k++) {
        acc[k] += __shfl_xor(acc[k], 16);
        acc[k] += __shfl_xor(acc[k], 32);
    }
    float sf[8] = {blo(sv.x), bhi(sv.x), blo(sv.y), bhi(sv.y), blo(sv.z), bhi(sv.z), blo(sv.w), bhi(sv.w)};
    unsigned short hh[8], hl[8];
#pragma unroll
    for (int k = 0; k < 8; k++) {
        float v = (acc[k] + sf[k]) * wd + bias[d0 + k];
        hh[k] = f2bf(v);
        hl[k] = f2bf(v - bf2f(hh[k]));
    }
    if (q == 0) {
        uint4 ph, pl;
        ph.x = ((unsigned)hh[1] << 16) | hh[0]; ph.y = ((unsigned)hh[3] << 16) | hh[2];
        ph.z = ((unsigned)hh[5] << 16) | hh[4]; ph.w = ((unsigned)hh[7] << 16) | hh[6];
        pl.x = ((unsigned)hl[1] << 16) | hl[0]; pl.y = ((unsigned)hl[3] << 16) | hl[2];
        pl.z = ((unsigned)hl[5] << 16) | hl[4]; pl.w = ((unsigned)hl[7] << 16) | hl[6];
        *(uint4*)&h2h[(size_t)node * 128 + d0] = ph;
        *(uint4*)&h2l[(size_t)node * 128 + d0] = pl;
    }
}

// ---------------- bilinear: s = T @ e^T, out = s*w + b ----------------
__global__ __launch_bounds__(256, 2) void bilinear_k(const unsigned short* Th, const unsigned short* Tl,
                                                     const unsigned short* Eh, const float* lin_w,
                                                     const float* lin_b, float* outp) {
    int tid = threadIdx.x, wave = tid >> 6, lane = tid & 63;
    int b = blockIdx.x >> 1, half = blockIdx.x & 1;
    int fr = lane & 15, q = lane >> 4;
    int irow0 = b * 256 + half * 128 + wave * 32;
    bf16x8 Ah[2][4], Al[2][4];
#pragma unroll
    for (int it = 0; it < 2; it++)
#pragma unroll
        for (int kk = 0; kk < 4; kk++) {
            size_t off = (size_t)(irow0 + it * 16 + fr) * 128 + kk * 32 + q * 8;
            Ah[it][kk] = *(const bf16x8*)&Th[off];
            Al[it][kk] = *(const bf16x8*)&Tl[off];
        }
    float w0 = lin_w[0], w1 = lin_w[1], c0 = lin_b[0], c1 = lin_b[1];
    for (int jt = 0; jt < 16; jt++) {
        bf16x8 Bf[4];
#pragma unroll
        for (int kk = 0; kk < 4; kk++)
            Bf[kk] = *(const bf16x8*)&Eh[(size_t)(b * 256 + jt * 16 + fr) * 128 + kk * 32 + q * 8];
#pragma unroll
        for (int it = 0; it < 2; it++) {
            f32x4 acc = (f32x4){0.f, 0.f, 0.f, 0.f};
#pragma unroll
            for (int kk = 0; kk < 4; kk++) {
                acc = __builtin_amdgcn_mfma_f32_16x16x32_bf16(Ah[it][kk], Bf[kk], acc, 0, 0, 0);
                acc = __builtin_amdgcn_mfma_f32_16x16x32_bf16(Al[it][kk], Bf[kk], acc, 0, 0, 0);
            }
#pragma unroll
            for (int r = 0; r < 4; r++) {
                int iloc = half * 128 + wave * 32 + it * 16 + q * 4 + r;
                int jloc = jt * 16 + fr;
                size_t o = ((size_t)b * 65536 + (size_t)iloc * 256 + jloc) * 2;
                float s = acc[r];
                float2 ov;
                ov.x = fmaf(s, w0, c0);
                ov.y = fmaf(s, w1, c1);
                *(float2*)&outp[o] = ov;
            }
        }
    }
}

extern "C" void kernel_launch(void* const* d_in, const int* in_sizes, int n_in,
                              void* d_out, int out_size, void* d_ws, size_t ws_size,
                              hipStream_t stream) {
    const float* x   = (const float*)d_in[0];
    const float* Wt1 = (const float*)d_in[1];
    const float* bt1 = (const float*)d_in[2];
    const float* Wt2 = (const float*)d_in[3];
    const float* bt2 = (const float*)d_in[4];
    const float* W1  = (const float*)d_in[5];
    const float* b1  = (const float*)d_in[6];
    const float* W2  = (const float*)d_in[7];
    const float* b2  = (const float*)d_in[8];
    const float* Mtx = (const float*)d_in[9];
    const float* lw  = (const float*)d_in[10];
    const float* lb  = (const float*)d_in[11];
    const int*   ei  = (const int*)d_in[12];
    int E = in_sizes[12] / 2;
    const int* srcp = ei;
    const int* dstp = ei + E;

    unsigned char* p = (unsigned char*)d_ws;
    size_t off = 0;
    auto alloc = [&](size_t bytes) -> void* {
        void* r = p + off;
        off = (off + bytes + 255) & ~(size_t)255;
        return r;
    };
    int*   cnt    = (int*)alloc((size_t)NN * 4);
    int*   rowptr = (int*)alloc(((size_t)NN + 1) * 4);
    int*   cursor = (int*)alloc((size_t)NN * 4);
    float* invs   = (float*)alloc((size_t)NN * 4);
    int*   bsum   = (int*)alloc(256 * 4);
    int*   boff   = (int*)alloc(256 * 4);
    int*   colv   = (int*)alloc((size_t)E * 4);
    unsigned short* Wcat   = (unsigned short*)alloc(524288 * 2);
    unsigned short* W1T    = (unsigned short*)alloc(262144 * 2);
    unsigned short* W2T    = (unsigned short*)alloc(65536 * 2);
    unsigned short* MTh    = (unsigned short*)alloc(16384 * 2);
    unsigned short* MTl    = (unsigned short*)alloc(16384 * 2);
    float*          cbias  = (float*)alloc(512 * 4);
    unsigned short* WcombT = (unsigned short*)alloc(524288 * 2);
    unsigned short* t1     = (unsigned short*)alloc((size_t)NN * 512 * 2);
    unsigned short* h1     = (unsigned short*)alloc((size_t)NN * 512 * 2);
    unsigned short* uu     = (unsigned short*)alloc((size_t)NN * 128 * 2);
    // aliases (lifetimes disjoint): T over t1, h2 over h1
    unsigned short* Th  = t1;
    unsigned short* Tl  = t1 + (size_t)NN * 128;
    unsigned short* h2h = h1;
    unsigned short* h2l = h1 + (size_t)NN * 128;

    hipMemsetAsync(cnt, 0, (size_t)NN * 4, stream);
    prep_pack<<<3392, 256, 0, stream>>>(Wt1, Wt2, W1, W2, Mtx, Wcat, W1T, W2T, MTh, MTl);
    cbias_k<<<16, 256, 0, stream>>>(bt1, bt2, W1, cbias);
    count_k<<<(E + 255) / 256, 256, 0, stream>>>(dstp, cnt, E);
    red_k<<<256, 256, 0, stream>>>(cnt, bsum);
    scanb_k<<<1, 256, 0, stream>>>(bsum, boff);
    scanf_k<<<256, 256, 0, stream>>>(cnt, boff, rowptr, cursor, invs);
    fill_k<<<(E + 255) / 256, 256, 0, stream>>>(srcp, dstp, cursor, colv, E);
    // WcombT[512][1024] = (Wcat @ W1)^T = W1T @ Wcat^T
    gemm_bt<<<dim3(8, 4), 256, 0, stream>>>(W1T, Wcat, WcombT, nullptr, nullptr, 512, 1024, 512);
    // t1 = (x @ Wcomb + cbias) * invs[row]   [65536,512]
    gemm_f32a<<<2048, 256, 0, stream>>>(x, WcombT, t1, cbias, invs);
    // h1 = relu(invs*(sum + self) + b1)
    agg512<<<NN / 4, 256, 0, stream>>>(t1, rowptr, colv, invs, b1, h1);
    // u = (h1 @ W2) * invs[row]   [65536,128]
    gemm_bt<<<dim3(1, 512), 256, 0, stream>>>(h1, W2T, uu, nullptr, invs, NN, 128, 512);
    // h2 = invs*(sum + self) + b2 (hi/lo split)
    agg128<<<NN / 4, 256, 0, stream>>>(uu, rowptr, colv, invs, b2, h2h, h2l);
    // T = h2 @ M (split)
    gemm_T<<<512, 256, 0, stream>>>(h2h, h2l, MTh, MTl, Th, Tl);
    // scores + Linear(1,2)
    bilinear_k<<<512, 256, 0, stream>>>(Th, Tl, h2h, lw, lb, (float*)d_out);
}